// Round 3
// baseline (192.259 us; speedup 1.0000x reference)
//
#include <hip/hip_runtime.h>

// Problem constants (from reference):
// values: (B=2, T=3, N=6, H=256, W=704, C=17) float32
// indices: (P=500000, 3) int32 ; coors: (P, 2) float32
// out: (P, 17) float32  — bilinear sample with out-of-bounds corners zeroed.
#define B_ 2
#define T_ 3
#define N_ 6
#define H_ 256
#define W_ 704
#define C_ 17
#define P_ 500000

#define NIMG   (B_ * T_ * N_)        // 36
#define BANDS  64                    // H/4 -> 4-row y bands
#define NBINS  (NIMG * BANDS)        // 2304

// ---------------- pass 1: bin each point by (image, y-band) ----------------
__global__ __launch_bounds__(256) void bin_kernel(
    const int*   __restrict__ indices,
    const float* __restrict__ coors,
    int* __restrict__ binOf,
    int* __restrict__ counts)
{
    int p = blockIdx.x * blockDim.x + threadIdx.x;
    if (p >= P_) return;
    int ib = indices[p * 3 + 0];
    int it = indices[p * 3 + 1];
    int in = indices[p * 3 + 2];
    int flat = (ib * T_ + it) * N_ + in;
    float iy = coors[p * 2 + 0] - 0.5f;
    int y0 = (int)floorf(iy);
    int band = min(max(y0, 0), H_ - 1) >> 2;
    int b = flat * BANDS + band;
    binOf[p] = b;
    atomicAdd(&counts[b], 1);
}

// ---------------- pass 2: exclusive scan of 2304 counts (1 block) ----------
__global__ __launch_bounds__(256) void scan_kernel(int* __restrict__ counts)
{
    __shared__ int buf[256];
    const int t = threadIdx.x;
    const int base = t * (NBINS / 256);      // 9 bins per thread
    int local[NBINS / 256];
    int s = 0;
    #pragma unroll
    for (int i = 0; i < NBINS / 256; ++i) { local[i] = counts[base + i]; s += local[i]; }
    buf[t] = s;
    __syncthreads();
    int inc = s;
    for (int off = 1; off < 256; off <<= 1) {
        int v = (t >= off) ? buf[t - off] : 0;
        __syncthreads();
        buf[t] += v;
        inc = buf[t];
        __syncthreads();
    }
    int run = inc - s;                       // exclusive prefix of this thread
    #pragma unroll
    for (int i = 0; i < NBINS / 256; ++i) { counts[base + i] = run; run += local[i]; }
}

// ---------------- pass 3: scatter point ids into sorted order --------------
__global__ __launch_bounds__(256) void scatter_kernel(
    const int* __restrict__ binOf,
    int* __restrict__ cursor,
    int* __restrict__ order)
{
    int p = blockIdx.x * blockDim.x + threadIdx.x;
    if (p >= P_) return;
    int pos = atomicAdd(&cursor[binOf[p]], 1);
    order[pos] = p;
}

// ---------------- pass 4: bilinear gather in sorted order ------------------
// 3 points per wave64 (51/64 lanes active; lane -> (sub-point, channel)).
// All 4 corner loads issued unconditionally from clamped addresses; OOB
// corners handled by zeroing the weight (cndmask), not by branching.
template<bool SORTED>
__global__ __launch_bounds__(256) void bilerp_gather_kernel(
    const float* __restrict__ values,
    const int*   __restrict__ indices,
    const float* __restrict__ coors,
    const int*   __restrict__ order,
    float*       __restrict__ out)
{
    const int tid  = threadIdx.x;
    const int wave = blockIdx.x * (blockDim.x >> 6) + (tid >> 6);
    const int lane = tid & 63;
    const int sub  = lane / 17;            // 0..2 active, 3 = idle tail lanes
    const int c    = lane - sub * 17;      // channel 0..16
    const int pidx = wave * 3 + sub;
    if (sub >= 3 || pidx >= P_) return;
    const int p = SORTED ? order[pidx] : pidx;

    const int ib = indices[p * 3 + 0];
    const int it = indices[p * 3 + 1];
    const int in = indices[p * 3 + 2];
    const int flat = (ib * T_ + it) * N_ + in;   // < 36

    const float iy = coors[p * 2 + 0] - 0.5f;
    const float ix = coors[p * 2 + 1] - 0.5f;
    const float x0f = floorf(ix);
    const float y0f = floorf(iy);
    const float wx = ix - x0f;
    const float wy = iy - y0f;
    const int x0 = (int)x0f;
    const int y0 = (int)y0f;
    const int x1 = x0 + 1;
    const int y1 = y0 + 1;

    const int x0c = min(max(x0, 0), W_ - 1);
    const int x1c = min(max(x1, 0), W_ - 1);
    const int y0c = min(max(y0, 0), H_ - 1);
    const int y1c = min(max(y1, 0), H_ - 1);

    const float* __restrict__ img = values + (size_t)flat * (H_ * W_ * C_);

    // Issue all 4 gathers back-to-back (max MLP, no divergence).
    const float v00 = img[((size_t)y0c * W_ + x0c) * C_ + c];
    const float v01 = img[((size_t)y0c * W_ + x1c) * C_ + c];
    const float v10 = img[((size_t)y1c * W_ + x0c) * C_ + c];
    const float v11 = img[((size_t)y1c * W_ + x1c) * C_ + c];

    const bool xin0 = (x0 >= 0) & (x0 < W_);
    const bool xin1 = (x1 >= 0) & (x1 < W_);
    const bool yin0 = (y0 >= 0) & (y0 < H_);
    const bool yin1 = (y1 >= 0) & (y1 < H_);

    float w00 = (1.f - wx) * (1.f - wy);
    float w01 = wx * (1.f - wy);
    float w10 = (1.f - wx) * wy;
    float w11 = wx * wy;
    w00 = (xin0 & yin0) ? w00 : 0.f;
    w01 = (xin1 & yin0) ? w01 : 0.f;
    w10 = (xin0 & yin1) ? w10 : 0.f;
    w11 = (xin1 & yin1) ? w11 : 0.f;

    const float r = v00 * w00 + v01 * w01 + v10 * w10 + v11 * w11;
    __builtin_nontemporal_store(r, &out[(size_t)p * C_ + c]);
}

extern "C" void kernel_launch(void* const* d_in, const int* in_sizes, int n_in,
                              void* d_out, int out_size, void* d_ws, size_t ws_size,
                              hipStream_t stream)
{
    const float* values  = (const float*)d_in[0];
    const int*   indices = (const int*)d_in[1];
    const float* coors   = (const float*)d_in[2];
    float* out = (float*)d_out;

    const int block = 256;
    const int points_per_block = 12;   // 3 pts/wave * 4 waves
    const int gather_grid = (P_ + points_per_block - 1) / points_per_block;
    const int pt_grid = (P_ + block - 1) / block;

    // Workspace layout (ints): counts[NBINS] | binOf[P] | order[P]
    const size_t ws_need = (size_t)(NBINS + 2 * P_) * sizeof(int);
    if (ws_size >= ws_need) {
        int* counts = (int*)d_ws;
        int* binOf  = counts + NBINS;
        int* order  = binOf + P_;
        hipMemsetAsync(counts, 0, NBINS * sizeof(int), stream);
        bin_kernel<<<pt_grid, block, 0, stream>>>(indices, coors, binOf, counts);
        scan_kernel<<<1, 256, 0, stream>>>(counts);
        scatter_kernel<<<pt_grid, block, 0, stream>>>(binOf, counts, order);
        bilerp_gather_kernel<true><<<gather_grid, block, 0, stream>>>(
            values, indices, coors, order, out);
    } else {
        bilerp_gather_kernel<false><<<gather_grid, block, 0, stream>>>(
            values, indices, coors, nullptr, out);
    }
}

// Round 4
// 50.720 us; speedup vs baseline: 3.7906x; 3.7906x over previous
//
#include <hip/hip_runtime.h>

// Problem constants (from reference):
// values: (B=2, T=3, N=6, H=256, W=704, C=17) float32
// indices: (P=500000, 3) int32 ; coors: (P, 2) float32
// out: (P, 17) float32  — bilinear sample with out-of-bounds corners zeroed.
//
// Round-3 post-mortem: counting-sort by (image, y-band) regressed 50.7->192us.
// Sorted processing concentrates traffic into a narrow address range (HBM
// channel camping) and adds indirection + atomic passes; random order is what
// keeps all channels busy. Reverted to the round-2 kernel, which runs at
// ~6.1 TB/s effective (~97% of achievable) for its mandatory line-granular
// traffic (~308 MB).
#define B_ 2
#define T_ 3
#define N_ 6
#define H_ 256
#define W_ 704
#define C_ 17
#define P_ 500000

// 3 points per wave64 (51/64 lanes active; lane -> (sub-point, channel)).
// All 4 corner loads issued unconditionally from clamped addresses; OOB
// corners handled by zeroing the weight (cndmask), not by branching.
__global__ __launch_bounds__(256) void bilerp_gather_kernel(
    const float* __restrict__ values,
    const int*   __restrict__ indices,
    const float* __restrict__ coors,
    float*       __restrict__ out)
{
    const int tid  = threadIdx.x;
    const int wave = blockIdx.x * (blockDim.x >> 6) + (tid >> 6);
    const int lane = tid & 63;
    const int sub  = lane / 17;            // 0..2 active, 3 = idle tail lanes
    const int c    = lane - sub * 17;      // channel 0..16
    const int p    = wave * 3 + sub;       // point index
    if (sub >= 3 || p >= P_) return;

    const int ib = indices[p * 3 + 0];
    const int it = indices[p * 3 + 1];
    const int in = indices[p * 3 + 2];
    const int flat = (ib * T_ + it) * N_ + in;   // < 36

    const float iy = coors[p * 2 + 0] - 0.5f;
    const float ix = coors[p * 2 + 1] - 0.5f;
    const float x0f = floorf(ix);
    const float y0f = floorf(iy);
    const float wx = ix - x0f;
    const float wy = iy - y0f;
    const int x0 = (int)x0f;
    const int y0 = (int)y0f;
    const int x1 = x0 + 1;
    const int y1 = y0 + 1;

    // Clamped coordinates for unconditional loads.
    const int x0c = min(max(x0, 0), W_ - 1);
    const int x1c = min(max(x1, 0), W_ - 1);
    const int y0c = min(max(y0, 0), H_ - 1);
    const int y1c = min(max(y1, 0), H_ - 1);

    const float* __restrict__ img = values + (size_t)flat * (H_ * W_ * C_);

    // Issue all 4 gathers back-to-back (max MLP, no divergence).
    const float v00 = img[((size_t)y0c * W_ + x0c) * C_ + c];
    const float v01 = img[((size_t)y0c * W_ + x1c) * C_ + c];
    const float v10 = img[((size_t)y1c * W_ + x0c) * C_ + c];
    const float v11 = img[((size_t)y1c * W_ + x1c) * C_ + c];

    const bool xin0 = (x0 >= 0) & (x0 < W_);
    const bool xin1 = (x1 >= 0) & (x1 < W_);
    const bool yin0 = (y0 >= 0) & (y0 < H_);
    const bool yin1 = (y1 >= 0) & (y1 < H_);

    float w00 = (1.f - wx) * (1.f - wy);
    float w01 = wx * (1.f - wy);
    float w10 = (1.f - wx) * wy;
    float w11 = wx * wy;
    w00 = (xin0 & yin0) ? w00 : 0.f;
    w01 = (xin1 & yin0) ? w01 : 0.f;
    w10 = (xin0 & yin1) ? w10 : 0.f;
    w11 = (xin1 & yin1) ? w11 : 0.f;

    const float r = v00 * w00 + v01 * w01 + v10 * w10 + v11 * w11;
    __builtin_nontemporal_store(r, &out[(size_t)p * C_ + c]);
}

extern "C" void kernel_launch(void* const* d_in, const int* in_sizes, int n_in,
                              void* d_out, int out_size, void* d_ws, size_t ws_size,
                              hipStream_t stream)
{
    const float* values  = (const float*)d_in[0];
    const int*   indices = (const int*)d_in[1];
    const float* coors   = (const float*)d_in[2];
    float* out = (float*)d_out;

    // 3 points per wave64, 4 waves per 256-thread block -> 12 points/block.
    const int block = 256;
    const int points_per_block = 12;
    const int grid = (P_ + points_per_block - 1) / points_per_block;

    bilerp_gather_kernel<<<grid, block, 0, stream>>>(values, indices, coors, out);
}